// Round 6
// baseline (301.789 us; speedup 1.0000x reference)
//
#include <hip/hip_runtime.h>

#define DD 256
#define SS 256
#define BB 64
#define NEDGE 500000
#define MM 2048
#define NEG_INF -10000000000.0f
#define ROWF4 512          // float4 stride between (b,s) type rows in token_reprs
#define NROWS (BB * SS)    // 16384

// workspace byte offsets
#define OFF_VC     0
#define OFF_META   2048
#define OFF_SCALE  4096
#define OFF_PERM   8192
#define OFF_SSIGN  12288
#define OFF_MSORT  16384
#define OFF_BSTART 24576
#define OFF_ASLAB  65536
#define OFF_P2     (65536 + (8 << 20))
#define OFF_MROWS  (65536 + (16 << 20))

typedef _Float16 h2 __attribute__((ext_vector_type(2)));

__device__ __forceinline__ h2 uh(unsigned u) {
    union { unsigned x; h2 h; } c; c.x = u; return c.h;
}
__device__ __forceinline__ unsigned hpack(float a, float b) {
    union { h2 h; unsigned u; } c;
    c.h = h2{(_Float16)a, (_Float16)b};
    return c.u;
}

#if __has_builtin(__builtin_amdgcn_fdot2)
__device__ __forceinline__ float FDOT2(h2 a, h2 b, float c) {
    return __builtin_amdgcn_fdot2(a, b, c, false);
}
#else
__device__ __forceinline__ float FDOT2(h2 a, h2 b, float c) {
    return c + (float)a.x * (float)b.x + (float)a.y * (float)b.y;
}
#endif

// block 0: v = w1@w2, c = b1.w2+b2, sign-partition permutation + scales
// block 1: counting-sort m by batch pointer
__global__ void setup_k(const float* __restrict__ w1, const float* __restrict__ b1,
                        const float* __restrict__ w2, const float* __restrict__ b2,
                        const int* __restrict__ bp,
                        float* __restrict__ vc, int* __restrict__ meta,
                        float* __restrict__ scale, int* __restrict__ perm,
                        float* __restrict__ ssign,
                        int* __restrict__ msorted, int* __restrict__ bstart) {
    const int t = threadIdx.x;
    if (blockIdx.x == 0) {
        __shared__ float sv[256];
        __shared__ int sp[256], sn[256];
        float acc = 0.f;
        #pragma unroll 4
        for (int j = 0; j < DD / 2; ++j) acc += w1[t * (DD / 2) + j] * w2[j];
        sv[t] = acc; vc[t] = acc;
        __syncthreads();
        if (t == 0) {
            float c = b2[0];
            for (int j = 0; j < DD / 2; ++j) c += b1[j] * w2[j];
            vc[DD] = c;
            int np = 0, nn = 0;
            for (int d = 0; d < 256; ++d) {
                if (sv[d] >= 0.f) sp[np++] = d; else sn[nn++] = d;
            }
            int q = np >> 6; if (q > 3) q = 3;
            int pureneg = 3 - q;
            meta[0] = q;
            int idx = 0;
            for (int i = 0; i < q * 64; ++i) perm[idx++] = sp[i];
            for (int j = 0; j < pureneg * 64; ++j) perm[idx++] = sn[j];
            for (int i = q * 64; i < np; ++i) perm[idx++] = sp[i];
            for (int j = pureneg * 64; j < nn; ++j) perm[idx++] = sn[j];
            for (int d = 0; d < 256; ++d) scale[d] = sqrtf(fabsf(sv[perm[d]]));
            for (int j = 0; j < 64; ++j)
                ssign[j] = (sv[perm[192 + j]] >= 0.f) ? 1.f : -1.f;
        }
    } else {
        __shared__ int hist[BB];
        __shared__ int offs[BB + 1];
        if (t < BB) hist[t] = 0;
        __syncthreads();
        for (int m = t; m < MM; m += 256) atomicAdd(&hist[bp[m]], 1);
        __syncthreads();
        if (t == 0) {
            int acc = 0;
            for (int i = 0; i < BB; ++i) { offs[i] = acc; acc += hist[i]; }
            offs[BB] = acc;
        }
        __syncthreads();
        if (t < BB + 1) bstart[t] = offs[t];
        __syncthreads();
        for (int m = t; m < MM; m += 256) {
            int pos = atomicAdd(&offs[bp[m]], 1);
            msorted[pos] = m;
        }
    }
}

// Compact strided fp32 rows into dense f16 tables:
//  type rows -> aslab (4 slices of 64 permuted+sqrt(|v|)-scaled dims; one
//  128 B line per row per slice) + p2 (plain row-major, for lm)
//  mask rows -> mrows (plain row-major)
__global__ __launch_bounds__(256) void compact(
        const float* __restrict__ tok, const int* __restrict__ lmi,
        const int* __restrict__ perm, const float* __restrict__ scale,
        unsigned* __restrict__ aslab, unsigned* __restrict__ p2u,
        unsigned* __restrict__ mru) {
    const int lane = threadIdx.x & 63;
    const int w    = threadIdx.x >> 6;
    if (blockIdx.x < NROWS / 4) {
        __shared__ float rb[4][256];
        const int row = blockIdx.x * 4 + w;
        const int4   pm = ((const int4*)perm)[lane];
        const float4 sc = ((const float4*)scale)[lane];
        const float4 a = ((const float4*)tok)[(size_t)row * ROWF4 + lane];
        ((float4*)rb[w])[lane] = a;
        ((uint2*)p2u)[(size_t)row * 64 + lane] =
            make_uint2(hpack(a.x, a.y), hpack(a.z, a.w));
        __syncthreads();
        float o0 = rb[w][pm.x] * sc.x, o1 = rb[w][pm.y] * sc.y;
        float o2 = rb[w][pm.z] * sc.z, o3 = rb[w][pm.w] * sc.w;
        const int slice = lane >> 4, pos = lane & 15;
        ((uint2*)aslab)[((size_t)slice * NROWS + row) * 16 + pos] =
            make_uint2(hpack(o0, o1), hpack(o2, o3));
    } else {
        const int m = (blockIdx.x - NROWS / 4) * 4 + w;
        const float4 a = ((const float4*)(tok + (size_t)lmi[m] * DD))[lane];
        ((uint2*)mru)[(size_t)m * 64 + lane] =
            make_uint2(hpack(a.x, a.y), hpack(a.z, a.w));
    }
}

// Edge kernel: 256 edges/block, 16 lanes/edge, 4 slices of 64 dims.
// Each gather = one aligned 128 B L2 line from the single 2 MB/slice table.
// Slices 0..2 sign-homogeneous (accP/accN, wave-uniform); slice 3 unpacked
// with per-lane sign registers.
__global__ __launch_bounds__(256) void edge_fused(
        const unsigned* __restrict__ aslab,
        const int* __restrict__ edges, const int* __restrict__ meta,
        const float* __restrict__ ssign, const float* __restrict__ vc,
        float* __restrict__ out) {
    const int t = threadIdx.x;
    const int l16 = t & 15, grp = t >> 4;
    __shared__ int sIdx[2][256];
    __shared__ float accs[256];
    const int e = blockIdx.x * 256 + t;
    const bool val = e < NEDGE;
    sIdx[0][t] = val ? __builtin_nontemporal_load(edges + e) : 0;
    sIdx[1][t] = val ? __builtin_nontemporal_load(edges + NEDGE + e) : 0;
    const int q = meta[0];
    const float4 sg = ((const float4*)ssign)[l16];
    const float c = vc[DD];
    __syncthreads();

    const uint2* T = (const uint2*)aslab;
    float accP[16], accN[16];
    #pragma unroll
    for (int i = 0; i < 16; ++i) { accP[i] = 0.f; accN[i] = 0.f; }

#define EDGE_INNER(ACC, KK)                                                  \
    {                                                                        \
        const uint2* Tb = T + (size_t)(KK) * NROWS * 16;                     \
        _Pragma("unroll")                                                    \
        for (int i = 0; i < 16; ++i) {                                       \
            const int slot = i * 16 + grp;                                   \
            const uint2 pu = Tb[(size_t)sIdx[0][slot] * 16 + l16];           \
            const uint2 qu = Tb[(size_t)sIdx[1][slot] * 16 + l16];           \
            ACC[i] = FDOT2(uh(pu.x), uh(qu.x), ACC[i]);                      \
            ACC[i] = FDOT2(uh(pu.y), uh(qu.y), ACC[i]);                      \
        }                                                                    \
    }

    #pragma unroll 1
    for (int k = 0; k < 3; ++k) {
        if (k < q) EDGE_INNER(accP, k) else EDGE_INNER(accN, k)
    }
    {   // slice 3: mixed signs, unpacked
        const uint2* Tb = T + (size_t)3 * NROWS * 16;
        #pragma unroll
        for (int i = 0; i < 16; ++i) {
            const int slot = i * 16 + grp;
            const uint2 pu = Tb[(size_t)sIdx[0][slot] * 16 + l16];
            const uint2 qu = Tb[(size_t)sIdx[1][slot] * 16 + l16];
            h2 p0 = uh(pu.x), p1 = uh(pu.y), q0 = uh(qu.x), q1 = uh(qu.y);
            float r = ((float)p0.x * (float)q0.x) * sg.x
                    + ((float)p0.y * (float)q0.y) * sg.y
                    + ((float)p1.x * (float)q1.x) * sg.z
                    + ((float)p1.y * (float)q1.y) * sg.w;
            accP[i] += r;
        }
    }
#undef EDGE_INNER

    #pragma unroll
    for (int i = 0; i < 16; ++i) {
        float r = accP[i] - accN[i];
        r += __shfl_down(r, 8, 16);
        r += __shfl_down(r, 4, 16);
        r += __shfl_down(r, 2, 16);
        r += __shfl_down(r, 1, 16);
        if (l16 == 0) accs[i * 16 + grp] = r;
    }
    __syncthreads();
    if (val) __builtin_nontemporal_store(accs[t] + c, out + e);
}

// lm GEMM, batch-major: block=(batch, 64-col s-tile), chunks of 32 masks,
// 2x4 register tile/thread, f16 fdot2, k-sliced LDS staging (pad 18 -> b64
// conflict-free).
__global__ __launch_bounds__(256) void lm_gemm(
        const unsigned* __restrict__ p2u,
        const unsigned* __restrict__ mru,
        const int* __restrict__ msorted,
        const int* __restrict__ bstart,
        const int* __restrict__ tpm,
        float* __restrict__ out) {
    const int b  = blockIdx.x;
    const int st = blockIdx.y;
    const int s0 = bstart[b], nmt = bstart[b + 1] - s0;
    if (nmt == 0) return;
    const int t = threadIdx.x;
    const int tmg = t & 15, tsg = t >> 4;

    __shared__ unsigned candS[64 * 18];
    __shared__ unsigned maskS[32 * 18];
    __shared__ int mids[32];

    int scol[4]; bool mk[4];
    #pragma unroll
    for (int ss = 0; ss < 4; ++ss) {
        scol[ss] = st * 64 + tsg + ss * 16;
        mk[ss] = tpm[b * SS + scol[ss]] != 0;
    }

    for (int ch = 0; ch * 32 < nmt; ++ch) {
        const int nm = min(32, nmt - ch * 32);
        __syncthreads();
        if (t < 32) mids[t] = msorted[s0 + ch * 32 + min(t, nm - 1)];
        float acc[2][4];
        #pragma unroll
        for (int im = 0; im < 2; ++im)
            #pragma unroll
            for (int ss = 0; ss < 4; ++ss) acc[im][ss] = 0.f;

        #pragma unroll 1
        for (int k = 0; k < 8; ++k) {
            __syncthreads();
            for (int f = t; f < 512; f += 256) {
                int r = f >> 4, cc = f & 15;
                maskS[r * 18 + cc] = mru[(size_t)mids[r] * 128 + k * 16 + cc];
            }
            for (int f = t; f < 1024; f += 256) {
                int r = f >> 4, cc = f & 15;
                candS[r * 18 + cc] =
                    p2u[((size_t)b * SS + st * 64 + r) * 128 + k * 16 + cc];
            }
            __syncthreads();
            const uint2* Ar0 = (const uint2*)&maskS[(tmg * 2) * 18];
            const uint2* Ar1 = (const uint2*)&maskS[(tmg * 2 + 1) * 18];
            #pragma unroll
            for (int j = 0; j < 8; ++j) {
                const uint2 a0 = Ar0[j], a1 = Ar1[j];
                #pragma unroll
                for (int ss = 0; ss < 4; ++ss) {
                    const uint2 bb = ((const uint2*)&candS[(tsg + ss * 16) * 18])[j];
                    acc[0][ss] = FDOT2(uh(a0.x), uh(bb.x), acc[0][ss]);
                    acc[0][ss] = FDOT2(uh(a0.y), uh(bb.y), acc[0][ss]);
                    acc[1][ss] = FDOT2(uh(a1.x), uh(bb.x), acc[1][ss]);
                    acc[1][ss] = FDOT2(uh(a1.y), uh(bb.y), acc[1][ss]);
                }
            }
        }
        #pragma unroll
        for (int im = 0; im < 2; ++im) {
            const int mi = tmg * 2 + im;
            if (mi < nm) {
                const size_t ob = (size_t)mids[mi] * SS;
                #pragma unroll
                for (int ss = 0; ss < 4; ++ss)
                    out[ob + scol[ss]] = mk[ss] ? acc[im][ss] : NEG_INF;
            }
        }
    }
}

extern "C" void kernel_launch(void* const* d_in, const int* in_sizes, int n_in,
                              void* d_out, int out_size, void* d_ws, size_t ws_size,
                              hipStream_t stream) {
    const float* tok = (const float*)d_in[0];
    const float* w1  = (const float*)d_in[1];
    const float* b1  = (const float*)d_in[2];
    const float* w2  = (const float*)d_in[3];
    const float* b2  = (const float*)d_in[4];
    const int* edges = (const int*)d_in[5];
    const int* lmi   = (const int*)d_in[6];
    const int* bp    = (const int*)d_in[7];
    const int* tpm   = (const int*)d_in[8];

    float* out_lemmas = (float*)d_out;
    float* out_lm     = (float*)d_out + NEDGE;

    char* ws = (char*)d_ws;
    float* vc       = (float*)(ws + OFF_VC);
    int* meta       = (int*)(ws + OFF_META);
    float* scale    = (float*)(ws + OFF_SCALE);
    int* perm       = (int*)(ws + OFF_PERM);
    float* ssign    = (float*)(ws + OFF_SSIGN);
    int* msorted    = (int*)(ws + OFF_MSORT);
    int* bstart     = (int*)(ws + OFF_BSTART);
    unsigned* aslab = (unsigned*)(ws + OFF_ASLAB);
    unsigned* p2u   = (unsigned*)(ws + OFF_P2);
    unsigned* mru   = (unsigned*)(ws + OFF_MROWS);

    setup_k<<<2, 256, 0, stream>>>(w1, b1, w2, b2, bp, vc, meta, scale, perm,
                                   ssign, msorted, bstart);
    compact<<<NROWS / 4 + MM / 4, 256, 0, stream>>>(tok, lmi, perm, scale,
                                                    aslab, p2u, mru);
    edge_fused<<<(NEDGE + 255) / 256, 256, 0, stream>>>(aslab, edges, meta,
                                                        ssign, vc, out_lemmas);
    lm_gemm<<<dim3(BB, 4), 256, 0, stream>>>(p2u, mru, msorted, bstart, tpm,
                                             out_lm);
}

// Round 7
// 297.403 us; speedup vs baseline: 1.0147x; 1.0147x over previous
//
#include <hip/hip_runtime.h>

#define DD 256
#define SS 256
#define BB 64
#define NEDGE 500000
#define MM 2048
#define NEG_INF -10000000000.0f
#define ROWF4 512          // float4 stride between (b,s) type rows in token_reprs
#define NROWS (BB * SS)    // 16384
#define EBLK 1954          // ceil(NEDGE/256)

// workspace byte offsets
#define OFF_VC     0
#define OFF_MSORT  2048
#define OFF_BSTART 10240
#define OFF_HIST   16384
#define OFF_EPAIR  (1 << 20)                 // 500000 uint2  (scope,goal) sorted
#define OFF_EORIG  (6 << 20)                 // 500000 uint   original edge id
#define OFF_P2     (8 << 20)                 // NROWS f16 rows (512 B each)
#define OFF_QROW   (16 << 20)                // NROWS f16 rows of a*v
#define OFF_MROWS  (24 << 20)                // MM f16 mask rows

typedef _Float16 h2 __attribute__((ext_vector_type(2)));

__device__ __forceinline__ h2 uh(unsigned u) {
    union { unsigned x; h2 h; } c; c.x = u; return c.h;
}
__device__ __forceinline__ unsigned hpack(float a, float b) {
    union { h2 h; unsigned u; } c;
    c.h = h2{(_Float16)a, (_Float16)b};
    return c.u;
}

#if __has_builtin(__builtin_amdgcn_fdot2)
__device__ __forceinline__ float FDOT2(h2 a, h2 b, float c) {
    return __builtin_amdgcn_fdot2(a, b, c, false);
}
#else
__device__ __forceinline__ float FDOT2(h2 a, h2 b, float c) {
    return c + (float)a.x * (float)b.x + (float)a.y * (float)b.y;
}
#endif

__device__ __forceinline__ float dot16(uint4 a, uint4 b, float acc) {
    acc = FDOT2(uh(a.x), uh(b.x), acc);
    acc = FDOT2(uh(a.y), uh(b.y), acc);
    acc = FDOT2(uh(a.z), uh(b.z), acc);
    acc = FDOT2(uh(a.w), uh(b.w), acc);
    return acc;
}

// block 0: vc = w1@w2 (+bias); block 1: counting-sort m by batch; block 2: zero hist
__global__ void setup_k(const float* __restrict__ w1, const float* __restrict__ b1,
                        const float* __restrict__ w2, const float* __restrict__ b2,
                        const int* __restrict__ bp,
                        float* __restrict__ vc, int* __restrict__ msorted,
                        int* __restrict__ bstart, int* __restrict__ hist) {
    const int t = threadIdx.x;
    if (blockIdx.x == 0) {
        float acc = 0.f;
        #pragma unroll 4
        for (int j = 0; j < DD / 2; ++j) acc += w1[t * (DD / 2) + j] * w2[j];
        vc[t] = acc;
        if (t == 0) {
            float c = b2[0];
            for (int j = 0; j < DD / 2; ++j) c += b1[j] * w2[j];
            vc[DD] = c;
        }
    } else if (blockIdx.x == 1) {
        __shared__ int h[BB];
        __shared__ int offs[BB + 1];
        if (t < BB) h[t] = 0;
        __syncthreads();
        for (int m = t; m < MM; m += 256) atomicAdd(&h[bp[m]], 1);
        __syncthreads();
        if (t == 0) {
            int acc = 0;
            for (int i = 0; i < BB; ++i) { offs[i] = acc; acc += h[i]; }
            offs[BB] = acc;
        }
        __syncthreads();
        if (t < BB + 1) bstart[t] = offs[t];
        __syncthreads();
        for (int m = t; m < MM; m += 256) {
            int pos = atomicAdd(&offs[bp[m]], 1);
            msorted[pos] = m;
        }
    } else {
        for (int f = t; f < NROWS; f += 256) hist[f] = 0;
    }
}

// blocks [0,4096): type rows -> p2u (f16) + qrow (a*v f16)
// blocks [4096,4608): mask rows -> mrows (f16)
// blocks [4608,4608+EBLK): scope histogram
__global__ __launch_bounds__(256) void compact_hist(
        const float* __restrict__ tok, const int* __restrict__ lmi,
        const int* __restrict__ edges, const float* __restrict__ vc,
        unsigned* __restrict__ p2u, unsigned* __restrict__ qrow,
        unsigned* __restrict__ mru, int* __restrict__ hist) {
    const int t = threadIdx.x;
    const int lane = t & 63, w = t >> 6;
    const int bid = blockIdx.x;
    if (bid < NROWS / 4) {
        const int row = bid * 4 + w;
        const float4 a = ((const float4*)tok)[(size_t)row * ROWF4 + lane];
        const float4 v = ((const float4*)vc)[lane];
        ((uint2*)p2u)[(size_t)row * 64 + lane] =
            make_uint2(hpack(a.x, a.y), hpack(a.z, a.w));
        ((uint2*)qrow)[(size_t)row * 64 + lane] =
            make_uint2(hpack(a.x * v.x, a.y * v.y), hpack(a.z * v.z, a.w * v.w));
    } else if (bid < NROWS / 4 + MM / 4) {
        const int m = (bid - NROWS / 4) * 4 + w;
        const float4 a = ((const float4*)(tok + (size_t)lmi[m] * DD))[lane];
        ((uint2*)mru)[(size_t)m * 64 + lane] =
            make_uint2(hpack(a.x, a.y), hpack(a.z, a.w));
    } else {
        const int e = (bid - NROWS / 4 - MM / 4) * 256 + t;
        if (e < NEDGE) atomicAdd(&hist[__builtin_nontemporal_load(edges + e)], 1);
    }
}

// exclusive prefix over 16384 buckets (single block, LDS-staged)
__global__ __launch_bounds__(256) void prefix_k(int* __restrict__ hist) {
    __shared__ int loc[NROWS];
    __shared__ int part[256];
    __shared__ int scan[256];
    const int t = threadIdx.x;
    for (int f = t; f < NROWS; f += 256) loc[f] = hist[f];
    __syncthreads();
    int s = 0;
    for (int j = 0; j < 64; ++j) s += loc[t * 64 + j];
    part[t] = s;
    __syncthreads();
    if (t == 0) {
        int a = 0;
        for (int i = 0; i < 256; ++i) { scan[i] = a; a += part[i]; }
    }
    __syncthreads();
    int a = scan[t];
    for (int j = 0; j < 64; ++j) {
        int c = loc[t * 64 + j];
        loc[t * 64 + j] = a;
        a += c;
    }
    __syncthreads();
    for (int f = t; f < NROWS; f += 256) hist[f] = loc[f];
}

// scatter edges into scope-sorted order
__global__ __launch_bounds__(256) void scatter_k(
        const int* __restrict__ edges, int* __restrict__ hist,
        uint2* __restrict__ epair, unsigned* __restrict__ eorig) {
    const int e = blockIdx.x * 256 + threadIdx.x;
    if (e >= NEDGE) return;
    const int sc = __builtin_nontemporal_load(edges + e);
    const int gl = __builtin_nontemporal_load(edges + NEDGE + e);
    const int pos = atomicAdd(&hist[sc], 1);
    epair[pos] = make_uint2((unsigned)sc, (unsigned)gl);
    eorig[pos] = (unsigned)e;
}

// sorted edge dot: 32 lanes/edge, full 256-dim dot in one pass.
// scope rows repeat ~30x consecutively -> L1/L2 hits; goal rows are the only
// random gather (500k x 512 B f16).
__global__ __launch_bounds__(256) void edge_sorted(
        const unsigned* __restrict__ qrow, const unsigned* __restrict__ p2u,
        const uint2* __restrict__ epair, const unsigned* __restrict__ eorig,
        const float* __restrict__ vc, float* __restrict__ out) {
    const int t = threadIdx.x;
    const int l32 = t & 31, grp = t >> 5;  // 8 groups of 32 lanes
    __shared__ uint2 sPair[256];
    __shared__ unsigned sOrig[256];
    __shared__ float sRes[256];
    const int idx = blockIdx.x * 256 + t;
    const bool val = idx < NEDGE;
    sPair[t] = val ? epair[idx] : make_uint2(0u, 0u);
    sOrig[t] = val ? eorig[idx] : 0u;
    const float c = vc[DD];
    __syncthreads();

    const uint4* Q = (const uint4*)qrow;
    const uint4* A = (const uint4*)p2u;
    #pragma unroll 2
    for (int ii = 0; ii < 32; ++ii) {
        const int slot = grp * 32 + ii;   // consecutive sorted edges per group
        const uint2 pr = sPair[slot];
        const uint4 qa = Q[(size_t)pr.x * 32 + l32];
        const uint4 ab = A[(size_t)pr.y * 32 + l32];
        float r = dot16(qa, ab, 0.f);
        r += __shfl_down(r, 16, 32);
        r += __shfl_down(r, 8, 32);
        r += __shfl_down(r, 4, 32);
        r += __shfl_down(r, 2, 32);
        r += __shfl_down(r, 1, 32);
        if (l32 == 0) sRes[slot] = r + c;
    }
    __syncthreads();
    if (val) __builtin_nontemporal_store(sRes[t], out + sOrig[t]);
}

// lm GEMM: block=(batch, 64-col s-tile, 32-mask chunk). Full 48 KB tile staged
// once; 2x4 register tile; LDS row stride 33 uint4 (bank-checked).
__global__ __launch_bounds__(256) void lm_gemm(
        const unsigned* __restrict__ p2u,
        const unsigned* __restrict__ mru,
        const int* __restrict__ msorted,
        const int* __restrict__ bstart,
        const int* __restrict__ tpm,
        float* __restrict__ out) {
    const int b  = blockIdx.x;
    const int st = blockIdx.y;
    const int ch = blockIdx.z;
    const int s0 = bstart[b], nmt = bstart[b + 1] - s0;
    const int base = ch * 32;
    if (base >= nmt) return;
    const int nm = min(32, nmt - base);
    const int t = threadIdx.x;

    __shared__ uint4 candS[64 * 33];
    __shared__ uint4 maskS[32 * 33];
    __shared__ int mids[32];

    if (t < 32) mids[t] = msorted[s0 + base + min(t, nm - 1)];
    __syncthreads();
    for (int f = t; f < 32 * 32; f += 256) {
        const int r = f >> 5, q = f & 31;
        maskS[r * 33 + q] = ((const uint4*)mru)[(size_t)mids[r] * 32 + q];
    }
    for (int f = t; f < 64 * 32; f += 256) {
        const int r = f >> 5, q = f & 31;
        candS[r * 33 + q] = ((const uint4*)p2u)[((size_t)b * SS + st * 64 + r) * 32 + q];
    }
    __syncthreads();

    const int tmg = t & 15, tsg = t >> 4;
    float acc[2][4];
    #pragma unroll
    for (int im = 0; im < 2; ++im)
        #pragma unroll
        for (int ss = 0; ss < 4; ++ss) acc[im][ss] = 0.f;

    #pragma unroll 4
    for (int j = 0; j < 32; ++j) {
        const uint4 a0 = maskS[tmg * 33 + j];
        const uint4 a1 = maskS[(tmg + 16) * 33 + j];
        #pragma unroll
        for (int ss = 0; ss < 4; ++ss) {
            const uint4 bb = candS[(tsg * 4 + ss) * 33 + j];
            acc[0][ss] = dot16(a0, bb, acc[0][ss]);
            acc[1][ss] = dot16(a1, bb, acc[1][ss]);
        }
    }

    const int col0 = st * 64 + tsg * 4;
    float4 msk;
    msk.x = tpm[b * SS + col0] ? 1.f : 0.f;
    msk.y = tpm[b * SS + col0 + 1] ? 1.f : 0.f;
    msk.z = tpm[b * SS + col0 + 2] ? 1.f : 0.f;
    msk.w = tpm[b * SS + col0 + 3] ? 1.f : 0.f;
    #pragma unroll
    for (int im = 0; im < 2; ++im) {
        const int mi = tmg + im * 16;
        if (mi < nm) {
            float4 o;
            o.x = msk.x != 0.f ? acc[im][0] : NEG_INF;
            o.y = msk.y != 0.f ? acc[im][1] : NEG_INF;
            o.z = msk.z != 0.f ? acc[im][2] : NEG_INF;
            o.w = msk.w != 0.f ? acc[im][3] : NEG_INF;
            *(float4*)&out[(size_t)mids[mi] * SS + col0] = o;
        }
    }
}

extern "C" void kernel_launch(void* const* d_in, const int* in_sizes, int n_in,
                              void* d_out, int out_size, void* d_ws, size_t ws_size,
                              hipStream_t stream) {
    const float* tok = (const float*)d_in[0];
    const float* w1  = (const float*)d_in[1];
    const float* b1  = (const float*)d_in[2];
    const float* w2  = (const float*)d_in[3];
    const float* b2  = (const float*)d_in[4];
    const int* edges = (const int*)d_in[5];
    const int* lmi   = (const int*)d_in[6];
    const int* bp    = (const int*)d_in[7];
    const int* tpm   = (const int*)d_in[8];

    float* out_lemmas = (float*)d_out;
    float* out_lm     = (float*)d_out + NEDGE;

    char* ws = (char*)d_ws;
    float* vc       = (float*)(ws + OFF_VC);
    int* msorted    = (int*)(ws + OFF_MSORT);
    int* bstart     = (int*)(ws + OFF_BSTART);
    int* hist       = (int*)(ws + OFF_HIST);
    uint2* epair    = (uint2*)(ws + OFF_EPAIR);
    unsigned* eorig = (unsigned*)(ws + OFF_EORIG);
    unsigned* p2u   = (unsigned*)(ws + OFF_P2);
    unsigned* qrow  = (unsigned*)(ws + OFF_QROW);
    unsigned* mru   = (unsigned*)(ws + OFF_MROWS);

    setup_k<<<3, 256, 0, stream>>>(w1, b1, w2, b2, bp, vc, msorted, bstart, hist);
    compact_hist<<<NROWS / 4 + MM / 4 + EBLK, 256, 0, stream>>>(
        tok, lmi, edges, vc, p2u, qrow, mru, hist);
    prefix_k<<<1, 256, 0, stream>>>(hist);
    scatter_k<<<EBLK, 256, 0, stream>>>(edges, hist, epair, eorig);
    edge_sorted<<<EBLK, 256, 0, stream>>>(qrow, p2u, epair, eorig, vc, out_lemmas);
    lm_gemm<<<dim3(BB, 4, 4), 256, 0, stream>>>(p2u, mru, msorted, bstart, tpm, out_lm);
}